// Round 15
// baseline (222.025 us; speedup 1.0000x reference)
//
#include <hip/hip_runtime.h>

// ---------------------------------------------------------------------------
// MoE with adaptive gate, B=8192 D=2048 E=8 H=128, fp32 in/out, bf16 MFMA core
// k_cvt_gate : xf LDS-transpose convert WITH fused gate-logit partials
//              (shfl-reduce + atomicAdd into zeroed gates buffer) + W converts
// k_gemm12f  : fused GEMM1+silu+GEMM2+silu+gate; BK=64 double-buffered core;
//              inline softmax(logits+gb) per output row
// k_gemm3    : out = h2g @ W3flat + softmax(gates) @ b3 (m97 core, 1024 blk)
// ---------------------------------------------------------------------------

typedef __attribute__((ext_vector_type(8))) short short8;   // 8 bf16 (4 VGPRs)
typedef __attribute__((ext_vector_type(4))) short bf16x4;   // 4 bf16
typedef __attribute__((ext_vector_type(4))) float f32x4;    // MFMA C/D

#define B_SZ 8192
#define D_SZ 2048
#define E_SZ 8
#define H_SZ 128

__device__ __forceinline__ short f2bf(float f) {
  unsigned u = __builtin_bit_cast(unsigned, f);
  unsigned r = (u + 0x7fffu + ((u >> 16) & 1u)) >> 16;   // RNE
  return (short)r;
}

__device__ __forceinline__ float silu_f(float v) {
  return v / (1.f + __expf(-v));
}

__device__ __forceinline__ void gload_lds16(const void* g, void* l) {
  __builtin_amdgcn_global_load_lds(
      (const __attribute__((address_space(1))) void*)g,
      (__attribute__((address_space(3))) void*)l,
      16, 0, 0);
}

// softmax over 8 logits (+gb), returns normalized vector
__device__ __forceinline__ void softmax8(const float* __restrict__ logits,
                                         const float* __restrict__ gbv,
                                         float* __restrict__ out) {
  float lg[8], mx = -1e30f;
  #pragma unroll
  for (int e = 0; e < 8; ++e) { lg[e] = logits[e] + gbv[e]; mx = fmaxf(mx, lg[e]); }
  float s = 0.f;
  #pragma unroll
  for (int e = 0; e < 8; ++e) { lg[e] = __expf(lg[e] - mx); s += lg[e]; }
  const float inv = 1.f / s;
  #pragma unroll
  for (int e = 0; e < 8; ++e) out[e] = lg[e] * inv;
}

// ---------------------------------------------------------------------------
// 128x128 core, BK=32, double-buffered 32 KB LDS.  256 thr, 4 waves (2x2),
// wave-out 64x64, acc[4][4].  (used by k_gemm3: 1024 blocks -> 4/CU)
// ---------------------------------------------------------------------------
template<int NHT>
__device__ __forceinline__ void core128(const short* __restrict__ A,
                                        const short* __restrict__ B,
                                        short* lds, f32x4 acc[4][4])
{
  const int tid  = threadIdx.x;
  const int lane = tid & 63;
  const int wid  = tid >> 6;
  const int wr = wid >> 1, wc = wid & 1;
  const int lm = lane & 15, lk = lane >> 4;
  const int wl = (tid & ~63) * 8;   // wave-uniform LDS offset (shorts)

  auto STAGE = [&](int eta) {       // 4 x global_load_lds(16B) per thread
    const size_t go = (size_t)(eta >> 1)*8192 + (size_t)(eta & 1)*4096;
    short* l = lds + (eta & 1)*8192;
    gload_lds16(A + go + tid*8,        l + wl);
    gload_lds16(A + go + 2048 + tid*8, l + 2048 + wl);
    gload_lds16(B + go + tid*8,        l + 4096 + wl);
    gload_lds16(B + go + 2048 + tid*8, l + 6144 + wl);
  };

  STAGE(0);
  __syncthreads();
  for (int eta = 0; eta < NHT; ++eta) {
    if (eta + 1 < NHT) STAGE(eta + 1);        // prefetch into other buffer
    const short* la = lds + (eta & 1)*8192 + lk*1024 + (wr*64 + lm)*8;
    const short* lb = lds + (eta & 1)*8192 + 4096 + lk*1024 + (wc*64 + lm)*8;
    short8 av[4], bv[4];
    #pragma unroll
    for (int f = 0; f < 4; ++f) av[f] = *(const short8*)(la + f*128);
    #pragma unroll
    for (int f = 0; f < 4; ++f) bv[f] = *(const short8*)(lb + f*128);
    #pragma unroll
    for (int i = 0; i < 4; ++i)
      #pragma unroll
      for (int j = 0; j < 4; ++j)
        acc[i][j] = __builtin_amdgcn_mfma_f32_16x16x32_bf16(av[i], bv[j], acc[i][j], 0, 0, 0);
    __syncthreads();   // prefetch drained; current-buffer reads complete
  }
}

// ---------------------------------------------------------------------------
// 128x128 core, BK=64 full-tile double-buffer, 64 KB LDS.  256 thr, 4 waves,
// wave-out 64x64, acc[4][4].  (used by k_gemm12f: 512 blocks grid-capped)
// ---------------------------------------------------------------------------
template<int NKT>
__device__ __forceinline__ void core64k(const short* __restrict__ A,
                                        const short* __restrict__ B,
                                        short* lds, f32x4 acc[4][4])
{
  const int tid  = threadIdx.x;
  const int lane = tid & 63;
  const int wid  = tid >> 6;
  const int wr = wid >> 1, wc = wid & 1;
  const int lm = lane & 15, lk = lane >> 4;
  const int wbase = tid & ~63;

  auto STAGE = [&](int kt) {        // 8 x global_load_lds(16B) per thread
    const short* ga = A + (size_t)kt*8192;
    const short* gb = B + (size_t)kt*8192;
    short* la = lds + (kt & 1)*8192;
    short* lb = lds + 16384 + (kt & 1)*8192;
    #pragma unroll
    for (int q = 0; q < 4; ++q) {
      gload_lds16(ga + (q*256 + tid)*8, la + (q*256 + wbase)*8);
      gload_lds16(gb + (q*256 + tid)*8, lb + (q*256 + wbase)*8);
    }
  };

  STAGE(0);
  __syncthreads();
  for (int kt = 0; kt < NKT; ++kt) {
    if (kt + 1 < NKT) STAGE(kt + 1);
    const short* Ac = lds + (kt & 1)*8192;
    const short* Bc = lds + 16384 + (kt & 1)*8192;
    #pragma unroll
    for (int ks = 0; ks < 2; ++ks) {
      short8 av[4], bv[4];
      #pragma unroll
      for (int f = 0; f < 4; ++f)
        av[f] = *(const short8*)(Ac + (ks*4 + lk)*1024 + (wr*64 + f*16 + lm)*8);
      #pragma unroll
      for (int f = 0; f < 4; ++f)
        bv[f] = *(const short8*)(Bc + (ks*4 + lk)*1024 + (wc*64 + f*16 + lm)*8);
      #pragma unroll
      for (int i = 0; i < 4; ++i)
        #pragma unroll
        for (int j = 0; j < 4; ++j)
          acc[i][j] = __builtin_amdgcn_mfma_f32_16x16x32_bf16(av[i], bv[j], acc[i][j], 0, 0, 0);
    }
    __syncthreads();
  }
}

// ---------------------------------------------------------------------------
// K0: blocks [0,2048)    : xf convert via LDS transpose + gate-logit partials
//                          (shfl-reduce over 16-lane k-groups, atomicAdd)
//     blocks [2048,4160) : W1/W2/W3 converts (coalesced)
// gates must be pre-zeroed (hipMemsetAsync in kernel_launch).
// ---------------------------------------------------------------------------
__global__ __launch_bounds__(256)
void k_cvt_gate(const float* __restrict__ x,  const float* __restrict__ W1,
                const float* __restrict__ W2, const float* __restrict__ W3,
                const float* __restrict__ gw,
                short* __restrict__ xf, short* __restrict__ w1f,
                short* __restrict__ w2f, short* __restrict__ w3f,
                float* __restrict__ gates)
{
  __shared__ short lt[8192];   // 16 KB (xf branch only)
  const int b = blockIdx.x;
  const int tid = threadIdx.x;

  if (b < 2048) {
    // ---- xf tile (bt,kt) = 128 rows x 64 k + gate partials ----
    const int bt = b >> 5, kt = b & 31;
    const float* xb = x + (size_t)bt*128*2048 + kt*64;
    const int lane = tid & 63;

    // gw rows for this thread's fixed k-slice: k = kt*64 + (tid&15)*4 + d
    float g8[4][8];
    #pragma unroll
    for (int d = 0; d < 4; ++d) {
      const float4 a = *(const float4*)(gw + (size_t)(kt*64 + (tid & 15)*4 + d)*8);
      const float4 c = *(const float4*)(gw + (size_t)(kt*64 + (tid & 15)*4 + d)*8 + 4);
      g8[d][0]=a.x; g8[d][1]=a.y; g8[d][2]=a.z; g8[d][3]=a.w;
      g8[d][4]=c.x; g8[d][5]=c.y; g8[d][6]=c.z; g8[d][7]=c.w;
    }

    #pragma unroll
    for (int u = 0; u < 8; ++u) {
      const int flat = u*1024 + tid*4;   // 0..8191, step 4
      const int row = flat >> 6, kk = flat & 63;
      const float4 v = *(const float4*)(xb + (size_t)row*2048 + kk);
      // convert-store to frag LDS (XOR-swizzled)
      const int kg = kk >> 3;
      bf16x4 o;
      o[0] = f2bf(v.x); o[1] = f2bf(v.y); o[2] = f2bf(v.z); o[3] = f2bf(v.w);
      const int s = (kg*1024 + row*8 + (kk & 7)) ^ ((kg & 7) << 3);
      *(bf16x4*)(lt + s) = o;
      // gate partial for (row, e) over this thread's 4 k
      float pa[8];
      #pragma unroll
      for (int e = 0; e < 8; ++e)
        pa[e] = v.x*g8[0][e] + v.y*g8[1][e] + v.z*g8[2][e] + v.w*g8[3][e];
      // reduce across the 16-lane group (covers k 0..63 of this row)
      #pragma unroll
      for (int e = 0; e < 8; ++e) {
        #pragma unroll
        for (int d = 1; d < 16; d <<= 1)
          pa[e] += __shfl_xor(pa[e], d, 64);
      }
      if ((lane & 15) == 0) {
        float* gdst = gates + (size_t)(bt*128 + row)*8;
        #pragma unroll
        for (int e = 0; e < 8; ++e) atomicAdd(gdst + e, pa[e]);
      }
    }
    __syncthreads();
    short* dst = xf + (size_t)b*8192;
    #pragma unroll
    for (int u = 0; u < 4; ++u) {
      const int li = u*2048 + tid*8;
      const int kg = li >> 10;
      const int s = li ^ ((kg & 7) << 3);
      *(short8*)(dst + li) = *(const short8*)(lt + s);
    }
  } else {
    // ---- W converts (coalesced per-j 256B runs) ----
    const int gi = (b - 2048)*256 + tid + 2097152;
    if (gi < 2097152 + 262144) {              // w1f: [e8][kt32] tiles of W1[e]
      const int g = gi - 2097152;
      const int t = g >> 10, r = g & 1023;
      const int e = t >> 5, kt = t & 31;
      const int kg = r >> 7, p = r & 127;
      const int k0 = kt*64 + kg*8;
      short8 o;
      #pragma unroll
      for (int j = 0; j < 8; ++j)
        o[j] = f2bf(W1[(size_t)e*262144 + (size_t)(k0 + j)*128 + p]);
      *(short8*)(w1f + (size_t)g*8) = o;
    } else if (gi < 2097152 + 262144 + 16384) { // w2f: [e8][kt2] tiles of W2[e]
      const int g = gi - (2097152 + 262144);
      const int t = g >> 10, r = g & 1023;
      const int e = t >> 1, kt = t & 1;
      const int kg = r >> 7, p = r & 127;
      const int k0 = kt*64 + kg*8;
      short8 o;
      #pragma unroll
      for (int j = 0; j < 8; ++j)
        o[j] = f2bf(W2[(size_t)e*16384 + (size_t)(k0 + j)*128 + p]);
      *(short8*)(w2f + (size_t)g*8) = o;
    } else if (gi < 2637824) {                // w3f: [nt16][kt16] tiles of W3flat
      const int g = gi - 2375680;
      const int t = g >> 10, r = g & 1023;
      const int nt = t >> 4, kt = t & 15;
      const int kg = r >> 7, p = r & 127;
      const int k0 = kt*64 + kg*8;
      short8 o;
      #pragma unroll
      for (int j = 0; j < 8; ++j) {
        const int k = k0 + j;                 // k = e*128 + h
        o[j] = f2bf(W3[(size_t)(k >> 7)*262144 + (size_t)(k & 127)*2048 + nt*128 + p]);
      }
      *(short8*)(w3f + (size_t)g*8) = o;
    }
  }
}

// ---------------------------------------------------------------------------
// K2: fused GEMM1+silu+GEMM2+silu+gate -> h2gf frag tiles.  128x128, BK=64.
// grid 512 XCD-chunked: bt = xcd*8+(idx&7) (0..63), e = idx>>3 (0..7).
// Gate = inline softmax(logits + gb) per output row.
// ---------------------------------------------------------------------------
__global__ __launch_bounds__(256, 2)
void k_gemm12f(const short* __restrict__ xf, const short* __restrict__ w1f,
               const short* __restrict__ w2f,
               const float* __restrict__ b1, const float* __restrict__ b2,
               const float* __restrict__ gates, const float* __restrict__ gb,
               short* __restrict__ h2gf)
{
  __shared__ short lds[32768];   // 64 KB
  const int b = blockIdx.x;
  const int xcd = b & 7, idx = b >> 3;   // idx 0..63
  const int bt = xcd*8 + (idx & 7);      // 0..63
  const int e  = idx >> 3;               // 0..7

  f32x4 acc[4][4] = {};
  core64k<32>(xf  + (size_t)bt*32*8192,
              w1f + (size_t)e*32*8192,
              lds, acc);
  // core's final __syncthreads: LDS free for epilogue

  const int tid = threadIdx.x, lane = tid & 63, wid = tid >> 6;
  const int wr = wid >> 1, wc = wid & 1;
  const int lm = lane & 15, lk = lane >> 4, lr = lane >> 4;

  // ---- W2 fragments direct global->VGPR (L2-resident) ----
  short8 bvAll[2][2][4];
  #pragma unroll
  for (int kt = 0; kt < 2; ++kt)
  #pragma unroll
  for (int ks = 0; ks < 2; ++ks)
  #pragma unroll
  for (int fn = 0; fn < 4; ++fn)
    bvAll[kt][ks][fn] = *(const short8*)(
        w2f + (size_t)e*16384 + kt*8192 + (ks*4 + lk)*1024
            + (wc*64 + fn*16 + lm)*8);

  // ---- gate bias + per-row softmax for my 16 output rows ----
  float gbv[8];
  #pragma unroll
  for (int q = 0; q < 8; ++q) gbv[q] = gb[q];
  float gv[4][4];
  #pragma unroll
  for (int fm = 0; fm < 4; ++fm)
  #pragma unroll
  for (int i = 0; i < 4; ++i) {
    const int row = bt*128 + wr*64 + fm*16 + lr*4 + i;
    float lg[8], sm[8];
    const float4 l0 = *(const float4*)(gates + (size_t)row*8);
    const float4 l1 = *(const float4*)(gates + (size_t)row*8 + 4);
    lg[0]=l0.x; lg[1]=l0.y; lg[2]=l0.z; lg[3]=l0.w;
    lg[4]=l1.x; lg[5]=l1.y; lg[6]=l1.z; lg[7]=l1.w;
    softmax8(lg, gbv, sm);
    gv[fm][i] = sm[e];
  }

  // ---- h1 = silu(acc + b1) -> LDS frag [kg16][p128][j8] (32 KB) ----
  float b1v[4];
  #pragma unroll
  for (int fn = 0; fn < 4; ++fn) b1v[fn] = b1[e*H_SZ + wc*64 + fn*16 + lm];
  #pragma unroll
  for (int fm = 0; fm < 4; ++fm)
  #pragma unroll
  for (int i = 0; i < 4; ++i) {
    const int m = wr*64 + fm*16 + lr*4 + i;
    #pragma unroll
    for (int fn = 0; fn < 4; ++fn) {
      const int n = wc*64 + fn*16 + lm;          // h index 0..127
      const float v = silu_f(acc[fm][fn][i] + b1v[fn]);
      lds[(n >> 3)*1024 + m*8 + (n & 7)] = f2bf(v);
    }
  }
  __syncthreads();

  // ---- GEMM2: h2 = h1 @ W2[e], K=128 ----
  f32x4 acc2[4][4] = {};
  #pragma unroll
  for (int kt = 0; kt < 2; ++kt)
  #pragma unroll
  for (int ks = 0; ks < 2; ++ks) {
    short8 av[4];
    #pragma unroll
    for (int f = 0; f < 4; ++f)
      av[f] = *(const short8*)(lds + (kt*8 + ks*4 + lk)*1024 + (wr*64 + f*16 + lm)*8);
    #pragma unroll
    for (int i = 0; i < 4; ++i)
      #pragma unroll
      for (int j = 0; j < 4; ++j)
        acc2[i][j] = __builtin_amdgcn_mfma_f32_16x16x32_bf16(
            av[i], bvAll[kt][ks][j], acc2[i][j], 0, 0, 0);
  }
  __syncthreads();   // all h1 reads done; reuse LDS for h2

  // ---- h2 = silu(acc2 + b2) * gate -> LDS frag ----
  float b2v[4];
  #pragma unroll
  for (int fn = 0; fn < 4; ++fn) b2v[fn] = b2[e*H_SZ + wc*64 + fn*16 + lm];
  #pragma unroll
  for (int fm = 0; fm < 4; ++fm)
  #pragma unroll
  for (int i = 0; i < 4; ++i) {
    const int m = wr*64 + fm*16 + lr*4 + i;
    const float g = gv[fm][i];
    #pragma unroll
    for (int fn = 0; fn < 4; ++fn) {
      const int n = wc*64 + fn*16 + lm;
      const float v = silu_f(acc2[fm][fn][i] + b2v[fn]) * g;
      lds[(n >> 3)*1024 + m*8 + (n & 7)] = f2bf(v);
    }
  }
  __syncthreads();

  // ---- dump h2 frag tiles (bt*16 + e*2 + t2), coalesced short8 ----
  #pragma unroll
  for (int q = 0; q < 8; ++q) {
    const int li = q*2048 + tid*8;               // 0..16383
    const int t2 = li >> 13, off = li & 8191;
    *(short8*)(h2gf + ((size_t)bt*16 + e*2 + t2)*8192 + off) =
        *(const short8*)(lds + li);
  }
}

// ---------------------------------------------------------------------------
// K4: out = h2g @ W3flat + softmax(gates+gb) @ b3.  1024 blocks XCD-chunked.
// ---------------------------------------------------------------------------
__global__ __launch_bounds__(256, 4)
void k_gemm3(const short* __restrict__ h2gf, const short* __restrict__ w3f,
             const float* __restrict__ b3, const float* __restrict__ gates,
             const float* __restrict__ gb, float* __restrict__ out)
{
  __shared__ short lds[16384];   // 32 KB
  const int b = blockIdx.x;
  const int xcd = b & 7, idx = b >> 3;   // idx 0..127
  const int bt = xcd*8 + (idx & 7);      // 0..63
  const int nt = idx >> 3;               // 0..15

  f32x4 acc[4][4] = {};
  core128<32>(h2gf + (size_t)bt*16*8192,
              w3f  + (size_t)nt*16*8192,
              lds, acc);

  const int tid = threadIdx.x, lane = tid & 63, wid = tid >> 6;
  const int wr = wid >> 1, wc = wid & 1, lm = lane & 15, lr = lane >> 4;
  float b3c[4][8];
  #pragma unroll
  for (int fn = 0; fn < 4; ++fn) {
    const int n = nt*128 + wc*64 + fn*16 + lm;
    #pragma unroll
    for (int e = 0; e < 8; ++e) b3c[fn][e] = b3[(size_t)e*D_SZ + n];
  }
  float gbv[8];
  #pragma unroll
  for (int q = 0; q < 8; ++q) gbv[q] = gb[q];
  #pragma unroll
  for (int fm = 0; fm < 4; ++fm)
  #pragma unroll
  for (int i = 0; i < 4; ++i) {
    const int m = bt*128 + wr*64 + fm*16 + lr*4 + i;
    float lg[8], sm[8];
    const float4 l0 = *(const float4*)(gates + (size_t)m*8);
    const float4 l1 = *(const float4*)(gates + (size_t)m*8 + 4);
    lg[0]=l0.x; lg[1]=l0.y; lg[2]=l0.z; lg[3]=l0.w;
    lg[4]=l1.x; lg[5]=l1.y; lg[6]=l1.z; lg[7]=l1.w;
    softmax8(lg, gbv, sm);
    #pragma unroll
    for (int fn = 0; fn < 4; ++fn) {
      const int n = nt*128 + wc*64 + fn*16 + lm;
      float bias = 0.f;
      #pragma unroll
      for (int e = 0; e < 8; ++e) bias += sm[e] * b3c[fn][e];
      out[(size_t)m*D_SZ + n] = acc[fm][fn][i] + bias;
    }
  }
}

// ---------------------------------------------------------------------------
extern "C" void kernel_launch(void* const* d_in, const int* in_sizes, int n_in,
                              void* d_out, int out_size, void* d_ws, size_t ws_size,
                              hipStream_t stream)
{
  (void)in_sizes; (void)n_in; (void)out_size; (void)ws_size;
  const float* x  = (const float*)d_in[0];
  const float* gw = (const float*)d_in[1];
  const float* gb = (const float*)d_in[2];
  const float* W1 = (const float*)d_in[3];
  const float* b1 = (const float*)d_in[4];
  const float* W2 = (const float*)d_in[5];
  const float* b2 = (const float*)d_in[6];
  const float* W3 = (const float*)d_in[7];
  const float* b3 = (const float*)d_in[8];
  float* out = (float*)d_out;

  char* ws = (char*)d_ws;
  short* xf    = (short*)ws;  ws += (size_t)B_SZ*D_SZ*2;          // 33.5 MB
  short* w1f   = (short*)ws;  ws += (size_t)E_SZ*D_SZ*H_SZ*2;     //  4.2 MB
  short* w2f   = (short*)ws;  ws += (size_t)E_SZ*H_SZ*H_SZ*2;     //  0.26 MB
  short* w3f   = (short*)ws;  ws += (size_t)E_SZ*H_SZ*D_SZ*2;     //  4.2 MB
  float* gates = (float*)ws;  ws += (size_t)B_SZ*E_SZ*4;          //  0.26 MB (logits)
  short* h2gf  = (short*)ws;  ws += (size_t)B_SZ*E_SZ*H_SZ*2;     // 16.8 MB

  hipMemsetAsync(gates, 0, (size_t)B_SZ*E_SZ*4, stream);
  k_cvt_gate<<<dim3(4160), dim3(256), 0, stream>>>(x, W1, W2, W3, gw,
                                                   xf, w1f, w2f, w3f, gates);
  k_gemm12f <<<dim3(512),  dim3(256), 0, stream>>>(xf, w1f, w2f, b1, b2,
                                                   gates, gb, h2gf);
  k_gemm3   <<<dim3(1024), dim3(256), 0, stream>>>(h2gf, w3f, b3, gates, gb, out);
}

// Round 16
// 126.885 us; speedup vs baseline: 1.7498x; 1.7498x over previous
//
#include <hip/hip_runtime.h>

// ---------------------------------------------------------------------------
// MoE with adaptive gate, B=8192 D=2048 E=8 H=128, fp32 in/out, bf16 MFMA core
// k_cvt_gate : xf LDS-transpose convert + NON-ATOMIC gate-logit partials
//              (shfl-reduce -> part[kt][row][8] stores) + W converts
// k_gred     : reduce part over kt, +gb, softmax -> final gates (128 blocks)
// k_gemm12f  : fused GEMM1+silu+GEMM2+silu+gate; BK=64 double-buffered core
// k_gemm3    : out = h2g @ W3flat + gates @ b3 (m97 core, 1024 blocks)
// ---------------------------------------------------------------------------

typedef __attribute__((ext_vector_type(8))) short short8;   // 8 bf16 (4 VGPRs)
typedef __attribute__((ext_vector_type(4))) short bf16x4;   // 4 bf16
typedef __attribute__((ext_vector_type(4))) float f32x4;    // MFMA C/D

#define B_SZ 8192
#define D_SZ 2048
#define E_SZ 8
#define H_SZ 128

__device__ __forceinline__ short f2bf(float f) {
  unsigned u = __builtin_bit_cast(unsigned, f);
  unsigned r = (u + 0x7fffu + ((u >> 16) & 1u)) >> 16;   // RNE
  return (short)r;
}

__device__ __forceinline__ float silu_f(float v) {
  return v / (1.f + __expf(-v));
}

__device__ __forceinline__ void gload_lds16(const void* g, void* l) {
  __builtin_amdgcn_global_load_lds(
      (const __attribute__((address_space(1))) void*)g,
      (__attribute__((address_space(3))) void*)l,
      16, 0, 0);
}

// ---------------------------------------------------------------------------
// 128x128 core, BK=32, double-buffered 32 KB LDS.  256 thr, 4 waves (2x2),
// wave-out 64x64, acc[4][4].  (used by k_gemm3: 1024 blocks -> 4/CU)
// ---------------------------------------------------------------------------
template<int NHT>
__device__ __forceinline__ void core128(const short* __restrict__ A,
                                        const short* __restrict__ B,
                                        short* lds, f32x4 acc[4][4])
{
  const int tid  = threadIdx.x;
  const int lane = tid & 63;
  const int wid  = tid >> 6;
  const int wr = wid >> 1, wc = wid & 1;
  const int lm = lane & 15, lk = lane >> 4;
  const int wl = (tid & ~63) * 8;   // wave-uniform LDS offset (shorts)

  auto STAGE = [&](int eta) {       // 4 x global_load_lds(16B) per thread
    const size_t go = (size_t)(eta >> 1)*8192 + (size_t)(eta & 1)*4096;
    short* l = lds + (eta & 1)*8192;
    gload_lds16(A + go + tid*8,        l + wl);
    gload_lds16(A + go + 2048 + tid*8, l + 2048 + wl);
    gload_lds16(B + go + tid*8,        l + 4096 + wl);
    gload_lds16(B + go + 2048 + tid*8, l + 6144 + wl);
  };

  STAGE(0);
  __syncthreads();
  for (int eta = 0; eta < NHT; ++eta) {
    if (eta + 1 < NHT) STAGE(eta + 1);        // prefetch into other buffer
    const short* la = lds + (eta & 1)*8192 + lk*1024 + (wr*64 + lm)*8;
    const short* lb = lds + (eta & 1)*8192 + 4096 + lk*1024 + (wc*64 + lm)*8;
    short8 av[4], bv[4];
    #pragma unroll
    for (int f = 0; f < 4; ++f) av[f] = *(const short8*)(la + f*128);
    #pragma unroll
    for (int f = 0; f < 4; ++f) bv[f] = *(const short8*)(lb + f*128);
    #pragma unroll
    for (int i = 0; i < 4; ++i)
      #pragma unroll
      for (int j = 0; j < 4; ++j)
        acc[i][j] = __builtin_amdgcn_mfma_f32_16x16x32_bf16(av[i], bv[j], acc[i][j], 0, 0, 0);
    __syncthreads();   // prefetch drained; current-buffer reads complete
  }
}

// ---------------------------------------------------------------------------
// 128x128 core, BK=64 full-tile double-buffer, 64 KB LDS.  256 thr, 4 waves,
// wave-out 64x64, acc[4][4].  (used by k_gemm12f: 512 blocks grid-capped)
// ---------------------------------------------------------------------------
template<int NKT>
__device__ __forceinline__ void core64k(const short* __restrict__ A,
                                        const short* __restrict__ B,
                                        short* lds, f32x4 acc[4][4])
{
  const int tid  = threadIdx.x;
  const int lane = tid & 63;
  const int wid  = tid >> 6;
  const int wr = wid >> 1, wc = wid & 1;
  const int lm = lane & 15, lk = lane >> 4;
  const int wbase = tid & ~63;

  auto STAGE = [&](int kt) {        // 8 x global_load_lds(16B) per thread
    const short* ga = A + (size_t)kt*8192;
    const short* gb = B + (size_t)kt*8192;
    short* la = lds + (kt & 1)*8192;
    short* lb = lds + 16384 + (kt & 1)*8192;
    #pragma unroll
    for (int q = 0; q < 4; ++q) {
      gload_lds16(ga + (q*256 + tid)*8, la + (q*256 + wbase)*8);
      gload_lds16(gb + (q*256 + tid)*8, lb + (q*256 + wbase)*8);
    }
  };

  STAGE(0);
  __syncthreads();
  for (int kt = 0; kt < NKT; ++kt) {
    if (kt + 1 < NKT) STAGE(kt + 1);
    const short* Ac = lds + (kt & 1)*8192;
    const short* Bc = lds + 16384 + (kt & 1)*8192;
    #pragma unroll
    for (int ks = 0; ks < 2; ++ks) {
      short8 av[4], bv[4];
      #pragma unroll
      for (int f = 0; f < 4; ++f)
        av[f] = *(const short8*)(Ac + (ks*4 + lk)*1024 + (wr*64 + f*16 + lm)*8);
      #pragma unroll
      for (int f = 0; f < 4; ++f)
        bv[f] = *(const short8*)(Bc + (ks*4 + lk)*1024 + (wc*64 + f*16 + lm)*8);
      #pragma unroll
      for (int i = 0; i < 4; ++i)
        #pragma unroll
        for (int j = 0; j < 4; ++j)
          acc[i][j] = __builtin_amdgcn_mfma_f32_16x16x32_bf16(av[i], bv[j], acc[i][j], 0, 0, 0);
    }
    __syncthreads();
  }
}

// ---------------------------------------------------------------------------
// K0: blocks [0,2048)    : xf convert via LDS transpose + gate-logit partials
//                          (shfl-reduce over 16-lane k-groups, plain stores
//                          to part[kt][row][8] -- no atomics)
//     blocks [2048,4160) : W1/W2/W3 converts (coalesced)
// ---------------------------------------------------------------------------
__global__ __launch_bounds__(256)
void k_cvt_gate(const float* __restrict__ x,  const float* __restrict__ W1,
                const float* __restrict__ W2, const float* __restrict__ W3,
                const float* __restrict__ gw,
                short* __restrict__ xf, short* __restrict__ w1f,
                short* __restrict__ w2f, short* __restrict__ w3f,
                float* __restrict__ part)
{
  __shared__ short lt[8192];   // 16 KB (xf branch only)
  const int b = blockIdx.x;
  const int tid = threadIdx.x;

  if (b < 2048) {
    // ---- xf tile (bt,kt) = 128 rows x 64 k + gate partials ----
    const int bt = b >> 5, kt = b & 31;
    const float* xb = x + (size_t)bt*128*2048 + kt*64;
    const int lane = tid & 63;

    // gw rows for this thread's fixed k-slice: k = kt*64 + (tid&15)*4 + d
    float g8[4][8];
    #pragma unroll
    for (int d = 0; d < 4; ++d) {
      const float4 a = *(const float4*)(gw + (size_t)(kt*64 + (tid & 15)*4 + d)*8);
      const float4 c = *(const float4*)(gw + (size_t)(kt*64 + (tid & 15)*4 + d)*8 + 4);
      g8[d][0]=a.x; g8[d][1]=a.y; g8[d][2]=a.z; g8[d][3]=a.w;
      g8[d][4]=c.x; g8[d][5]=c.y; g8[d][6]=c.z; g8[d][7]=c.w;
    }

    #pragma unroll
    for (int u = 0; u < 8; ++u) {
      const int flat = u*1024 + tid*4;   // 0..8191, step 4
      const int row = flat >> 6, kk = flat & 63;
      const float4 v = *(const float4*)(xb + (size_t)row*2048 + kk);
      // convert-store to frag LDS (XOR-swizzled)
      const int kg = kk >> 3;
      bf16x4 o;
      o[0] = f2bf(v.x); o[1] = f2bf(v.y); o[2] = f2bf(v.z); o[3] = f2bf(v.w);
      const int s = (kg*1024 + row*8 + (kk & 7)) ^ ((kg & 7) << 3);
      *(bf16x4*)(lt + s) = o;
      // gate partial for (row, e) over this thread's 4 k
      float pa[8];
      #pragma unroll
      for (int e = 0; e < 8; ++e)
        pa[e] = v.x*g8[0][e] + v.y*g8[1][e] + v.z*g8[2][e] + v.w*g8[3][e];
      // reduce across the 16-lane group (covers k 0..63 of this row)
      #pragma unroll
      for (int e = 0; e < 8; ++e) {
        #pragma unroll
        for (int d = 1; d < 16; d <<= 1)
          pa[e] += __shfl_xor(pa[e], d, 64);
      }
      if ((lane & 15) == 0) {
        float* pdst = part + ((size_t)kt*8192 + (size_t)bt*128 + row)*8;
        *(float4*)pdst       = make_float4(pa[0], pa[1], pa[2], pa[3]);
        *(float4*)(pdst + 4) = make_float4(pa[4], pa[5], pa[6], pa[7]);
      }
    }
    __syncthreads();
    short* dst = xf + (size_t)b*8192;
    #pragma unroll
    for (int u = 0; u < 4; ++u) {
      const int li = u*2048 + tid*8;
      const int kg = li >> 10;
      const int s = li ^ ((kg & 7) << 3);
      *(short8*)(dst + li) = *(const short8*)(lt + s);
    }
  } else {
    // ---- W converts (coalesced per-j 256B runs) ----
    const int gi = (b - 2048)*256 + tid + 2097152;
    if (gi < 2097152 + 262144) {              // w1f: [e8][kt32] tiles of W1[e]
      const int g = gi - 2097152;
      const int t = g >> 10, r = g & 1023;
      const int e = t >> 5, kt = t & 31;
      const int kg = r >> 7, p = r & 127;
      const int k0 = kt*64 + kg*8;
      short8 o;
      #pragma unroll
      for (int j = 0; j < 8; ++j)
        o[j] = f2bf(W1[(size_t)e*262144 + (size_t)(k0 + j)*128 + p]);
      *(short8*)(w1f + (size_t)g*8) = o;
    } else if (gi < 2097152 + 262144 + 16384) { // w2f: [e8][kt2] tiles of W2[e]
      const int g = gi - (2097152 + 262144);
      const int t = g >> 10, r = g & 1023;
      const int e = t >> 1, kt = t & 1;
      const int kg = r >> 7, p = r & 127;
      const int k0 = kt*64 + kg*8;
      short8 o;
      #pragma unroll
      for (int j = 0; j < 8; ++j)
        o[j] = f2bf(W2[(size_t)e*16384 + (size_t)(k0 + j)*128 + p]);
      *(short8*)(w2f + (size_t)g*8) = o;
    } else if (gi < 2637824) {                // w3f: [nt16][kt16] tiles of W3flat
      const int g = gi - 2375680;
      const int t = g >> 10, r = g & 1023;
      const int nt = t >> 4, kt = t & 15;
      const int kg = r >> 7, p = r & 127;
      const int k0 = kt*64 + kg*8;
      short8 o;
      #pragma unroll
      for (int j = 0; j < 8; ++j) {
        const int k = k0 + j;                 // k = e*128 + h
        o[j] = f2bf(W3[(size_t)(k >> 7)*262144 + (size_t)(k & 127)*2048 + nt*128 + p]);
      }
      *(short8*)(w3f + (size_t)g*8) = o;
    }
  }
}

// ---------------------------------------------------------------------------
// K1: reduce part[32][8192][8] over kt, add gb, softmax -> gates[8192][8].
// 128 blocks x 256 thr: wave q handles kt quarter q*8..q*8+7 for 64 rows;
// coalesced 32B/lane reads; LDS cross-wave reduce; wave 0 finalizes.
// ---------------------------------------------------------------------------
__global__ __launch_bounds__(256)
void k_gred(const float* __restrict__ part, const float* __restrict__ gb,
            float* __restrict__ gates)
{
  __shared__ float red[4][64][8];
  const int tid = threadIdx.x;
  const int rloc = tid & 63, q = tid >> 6;
  const int row = blockIdx.x*64 + rloc;

  float s[8] = {};
  #pragma unroll
  for (int j = 0; j < 8; ++j) {
    const int kt = q*8 + j;
    const float* p = part + ((size_t)kt*8192 + row)*8;
    const float4 a = *(const float4*)p;
    const float4 c = *(const float4*)(p + 4);
    s[0]+=a.x; s[1]+=a.y; s[2]+=a.z; s[3]+=a.w;
    s[4]+=c.x; s[5]+=c.y; s[6]+=c.z; s[7]+=c.w;
  }
  #pragma unroll
  for (int e = 0; e < 8; ++e) red[q][rloc][e] = s[e];
  __syncthreads();
  if (q == 0) {
    float lg[8], mx = -1e30f;
    #pragma unroll
    for (int e = 0; e < 8; ++e) {
      lg[e] = red[0][rloc][e] + red[1][rloc][e] + red[2][rloc][e]
            + red[3][rloc][e] + gb[e];
      mx = fmaxf(mx, lg[e]);
    }
    float sum = 0.f;
    #pragma unroll
    for (int e = 0; e < 8; ++e) { lg[e] = __expf(lg[e] - mx); sum += lg[e]; }
    const float inv = 1.f / sum;
    float* gdst = gates + (size_t)row*8;
    *(float4*)gdst       = make_float4(lg[0]*inv, lg[1]*inv, lg[2]*inv, lg[3]*inv);
    *(float4*)(gdst + 4) = make_float4(lg[4]*inv, lg[5]*inv, lg[6]*inv, lg[7]*inv);
  }
}

// ---------------------------------------------------------------------------
// K2: fused GEMM1+silu+GEMM2+silu+gate -> h2gf frag tiles.  128x128, BK=64.
// grid 512 XCD-chunked: bt = xcd*8+(idx&7) (0..63), e = idx>>3 (0..7).
// ---------------------------------------------------------------------------
__global__ __launch_bounds__(256, 2)
void k_gemm12f(const short* __restrict__ xf, const short* __restrict__ w1f,
               const short* __restrict__ w2f,
               const float* __restrict__ b1, const float* __restrict__ b2,
               const float* __restrict__ gates, short* __restrict__ h2gf)
{
  __shared__ short lds[32768];   // 64 KB
  const int b = blockIdx.x;
  const int xcd = b & 7, idx = b >> 3;   // idx 0..63
  const int bt = xcd*8 + (idx & 7);      // 0..63
  const int e  = idx >> 3;               // 0..7

  f32x4 acc[4][4] = {};
  core64k<32>(xf  + (size_t)bt*32*8192,
              w1f + (size_t)e*32*8192,
              lds, acc);
  // core's final __syncthreads: LDS free for epilogue

  const int tid = threadIdx.x, lane = tid & 63, wid = tid >> 6;
  const int wr = wid >> 1, wc = wid & 1;
  const int lm = lane & 15, lk = lane >> 4, lr = lane >> 4;

  // ---- W2 fragments direct global->VGPR (L2-resident) ----
  short8 bvAll[2][2][4];
  #pragma unroll
  for (int kt = 0; kt < 2; ++kt)
  #pragma unroll
  for (int ks = 0; ks < 2; ++ks)
  #pragma unroll
  for (int fn = 0; fn < 4; ++fn)
    bvAll[kt][ks][fn] = *(const short8*)(
        w2f + (size_t)e*16384 + kt*8192 + (ks*4 + lk)*1024
            + (wc*64 + fn*16 + lm)*8);

  // ---- gates for my 16 output rows ----
  float gv[4][4];
  #pragma unroll
  for (int fm = 0; fm < 4; ++fm)
  #pragma unroll
  for (int i = 0; i < 4; ++i)
    gv[fm][i] = gates[(size_t)(bt*128 + wr*64 + fm*16 + lr*4 + i)*8 + e];

  // ---- h1 = silu(acc + b1) -> LDS frag [kg16][p128][j8] (32 KB) ----
  float b1v[4];
  #pragma unroll
  for (int fn = 0; fn < 4; ++fn) b1v[fn] = b1[e*H_SZ + wc*64 + fn*16 + lm];
  #pragma unroll
  for (int fm = 0; fm < 4; ++fm)
  #pragma unroll
  for (int i = 0; i < 4; ++i) {
    const int m = wr*64 + fm*16 + lr*4 + i;
    #pragma unroll
    for (int fn = 0; fn < 4; ++fn) {
      const int n = wc*64 + fn*16 + lm;          // h index 0..127
      const float v = silu_f(acc[fm][fn][i] + b1v[fn]);
      lds[(n >> 3)*1024 + m*8 + (n & 7)] = f2bf(v);
    }
  }
  __syncthreads();

  // ---- GEMM2: h2 = h1 @ W2[e], K=128 ----
  f32x4 acc2[4][4] = {};
  #pragma unroll
  for (int kt = 0; kt < 2; ++kt)
  #pragma unroll
  for (int ks = 0; ks < 2; ++ks) {
    short8 av[4];
    #pragma unroll
    for (int f = 0; f < 4; ++f)
      av[f] = *(const short8*)(lds + (kt*8 + ks*4 + lk)*1024 + (wr*64 + f*16 + lm)*8);
    #pragma unroll
    for (int i = 0; i < 4; ++i)
      #pragma unroll
      for (int j = 0; j < 4; ++j)
        acc2[i][j] = __builtin_amdgcn_mfma_f32_16x16x32_bf16(
            av[i], bvAll[kt][ks][j], acc2[i][j], 0, 0, 0);
  }
  __syncthreads();   // all h1 reads done; reuse LDS for h2

  // ---- h2 = silu(acc2 + b2) * gate -> LDS frag ----
  float b2v[4];
  #pragma unroll
  for (int fn = 0; fn < 4; ++fn) b2v[fn] = b2[e*H_SZ + wc*64 + fn*16 + lm];
  #pragma unroll
  for (int fm = 0; fm < 4; ++fm)
  #pragma unroll
  for (int i = 0; i < 4; ++i) {
    const int m = wr*64 + fm*16 + lr*4 + i;
    const float g = gv[fm][i];
    #pragma unroll
    for (int fn = 0; fn < 4; ++fn) {
      const int n = wc*64 + fn*16 + lm;
      const float v = silu_f(acc2[fm][fn][i] + b2v[fn]) * g;
      lds[(n >> 3)*1024 + m*8 + (n & 7)] = f2bf(v);
    }
  }
  __syncthreads();

  // ---- dump h2 frag tiles (bt*16 + e*2 + t2), coalesced short8 ----
  #pragma unroll
  for (int q = 0; q < 8; ++q) {
    const int li = q*2048 + tid*8;               // 0..16383
    const int t2 = li >> 13, off = li & 8191;
    *(short8*)(h2gf + ((size_t)bt*16 + e*2 + t2)*8192 + off) =
        *(const short8*)(lds + li);
  }
}

// ---------------------------------------------------------------------------
// K4: out = h2g @ W3flat + gates @ b3.  1024 blocks XCD-chunked.
// ---------------------------------------------------------------------------
__global__ __launch_bounds__(256, 4)
void k_gemm3(const short* __restrict__ h2gf, const short* __restrict__ w3f,
             const float* __restrict__ b3, const float* __restrict__ gates,
             float* __restrict__ out)
{
  __shared__ short lds[16384];   // 32 KB
  const int b = blockIdx.x;
  const int xcd = b & 7, idx = b >> 3;   // idx 0..127
  const int bt = xcd*8 + (idx & 7);      // 0..63
  const int nt = idx >> 3;               // 0..15

  f32x4 acc[4][4] = {};
  core128<32>(h2gf + (size_t)bt*16*8192,
              w3f  + (size_t)nt*16*8192,
              lds, acc);

  const int tid = threadIdx.x, lane = tid & 63, wid = tid >> 6;
  const int wr = wid >> 1, wc = wid & 1, lm = lane & 15, lr = lane >> 4;
  float b3c[4][8];
  #pragma unroll
  for (int fn = 0; fn < 4; ++fn) {
    const int n = nt*128 + wc*64 + fn*16 + lm;
    #pragma unroll
    for (int e = 0; e < 8; ++e) b3c[fn][e] = b3[(size_t)e*D_SZ + n];
  }
  #pragma unroll
  for (int fm = 0; fm < 4; ++fm)
  #pragma unroll
  for (int i = 0; i < 4; ++i) {
    const int m = bt*128 + wr*64 + fm*16 + lr*4 + i;
    const float4 ga  = *(const float4*)(gates + (size_t)m*8);
    const float4 gbv = *(const float4*)(gates + (size_t)m*8 + 4);
    #pragma unroll
    for (int fn = 0; fn < 4; ++fn) {
      const int n = nt*128 + wc*64 + fn*16 + lm;
      const float bias = ga.x*b3c[fn][0] + ga.y*b3c[fn][1] + ga.z*b3c[fn][2] + ga.w*b3c[fn][3]
                       + gbv.x*b3c[fn][4] + gbv.y*b3c[fn][5] + gbv.z*b3c[fn][6] + gbv.w*b3c[fn][7];
      out[(size_t)m*D_SZ + n] = acc[fm][fn][i] + bias;
    }
  }
}

// ---------------------------------------------------------------------------
extern "C" void kernel_launch(void* const* d_in, const int* in_sizes, int n_in,
                              void* d_out, int out_size, void* d_ws, size_t ws_size,
                              hipStream_t stream)
{
  (void)in_sizes; (void)n_in; (void)out_size; (void)ws_size;
  const float* x  = (const float*)d_in[0];
  const float* gw = (const float*)d_in[1];
  const float* gb = (const float*)d_in[2];
  const float* W1 = (const float*)d_in[3];
  const float* b1 = (const float*)d_in[4];
  const float* W2 = (const float*)d_in[5];
  const float* b2 = (const float*)d_in[6];
  const float* W3 = (const float*)d_in[7];
  const float* b3 = (const float*)d_in[8];
  float* out = (float*)d_out;

  char* ws = (char*)d_ws;
  short* xf    = (short*)ws;  ws += (size_t)B_SZ*D_SZ*2;          // 33.5 MB
  short* w1f   = (short*)ws;  ws += (size_t)E_SZ*D_SZ*H_SZ*2;     //  4.2 MB
  short* w2f   = (short*)ws;  ws += (size_t)E_SZ*H_SZ*H_SZ*2;     //  0.26 MB
  short* w3f   = (short*)ws;  ws += (size_t)E_SZ*H_SZ*D_SZ*2;     //  4.2 MB
  float* gates = (float*)ws;  ws += (size_t)B_SZ*E_SZ*4;          //  0.26 MB
  float* part  = (float*)ws;  ws += (size_t)32*B_SZ*E_SZ*4;       //  8.4 MB
  short* h2gf  = (short*)ws;  ws += (size_t)B_SZ*E_SZ*H_SZ*2;     // 16.8 MB

  k_cvt_gate<<<dim3(4160), dim3(256), 0, stream>>>(x, W1, W2, W3, gw,
                                                   xf, w1f, w2f, w3f, part);
  k_gred    <<<dim3(128),  dim3(256), 0, stream>>>(part, gb, gates);
  k_gemm12f <<<dim3(512),  dim3(256), 0, stream>>>(xf, w1f, w2f, b1, b2,
                                                   gates, h2gf);
  k_gemm3   <<<dim3(1024), dim3(256), 0, stream>>>(h2gf, w3f, b3, gates, out);
}